// Round 1
// baseline (100.183 us; speedup 1.0000x reference)
//
#include <hip/hip_runtime.h>
#include <math.h>

#define FEAS 4096
#define K 64
#define BATCH 4096

// ws layout (floats): [0..63] col_sum, [64] diag (sum of squares)

__global__ __launch_bounds__(256) void cross_reduce_kernel(
    const float* __restrict__ cross, float* __restrict__ ws) {
    // 64 blocks x 256 threads; block b handles rows [b*64, b*64+64) of V (4096x64)
    const int j     = threadIdx.x & 63;   // column 0..63
    const int rlane = threadIdx.x >> 6;   // 0..3
    const int row0  = blockIdx.x * 64;

    float s = 0.f, q = 0.f;
#pragma unroll
    for (int i = 0; i < 16; ++i) {
        const int r = row0 + rlane + i * 4;
        const float v = cross[r * K + j];
        s += v;
        q += v * v;
    }

    __shared__ float ls[256];
    __shared__ float lq[256];
    ls[threadIdx.x] = s;
    lq[threadIdx.x] = q;
    __syncthreads();

    if (threadIdx.x < 64) {  // wave 0 only
        const float cs = ls[j] + ls[j + 64] + ls[j + 128] + ls[j + 192];
        atomicAdd(&ws[j], cs);

        float cq = lq[j] + lq[j + 64] + lq[j + 128] + lq[j + 192];
#pragma unroll
        for (int off = 32; off; off >>= 1) cq += __shfl_down(cq, off, 64);
        if (j == 0) atomicAdd(&ws[64], cq);
    }
}

__global__ __launch_bounds__(256) void gemv_sigmoid_kernel(
    const float* __restrict__ x, const float* __restrict__ w,
    const float* __restrict__ bias, const float* __restrict__ ws,
    float* __restrict__ out) {
    const int row = blockIdx.x;   // one block per output row
    const int tid = threadIdx.x;

    // Prologue: recompute scalar cross_sum from the 64 column sums (wave 0).
    __shared__ float s_cross;
    if (tid < 64) {
        const float c = ws[tid];
        float t = c * c;
#pragma unroll
        for (int off = 32; off; off >>= 1) t += __shfl_down(t, off, 64);
        if (tid == 0) s_cross = 0.5f * (t + ws[64]);
    }

    // Main dot product: 4096 floats per row, float4-vectorized, coalesced.
    const float4* __restrict__ xr = (const float4*)(x + (size_t)row * FEAS);
    const float4* __restrict__ wv = (const float4*)w;
    float acc = 0.f;
#pragma unroll
    for (int i = 0; i < 4; ++i) {
        const int idx = tid + i * 256;
        const float4 a = xr[idx];
        const float4 b = wv[idx];
        acc += a.x * b.x + a.y * b.y + a.z * b.z + a.w * b.w;
    }

    // Wave reduce then cross-wave reduce via LDS.
#pragma unroll
    for (int off = 32; off; off >>= 1) acc += __shfl_down(acc, off, 64);
    __shared__ float partial[4];
    if ((tid & 63) == 0) partial[tid >> 6] = acc;
    __syncthreads();

    if (tid == 0) {
        const float y = partial[0] + partial[1] + partial[2] + partial[3]
                        + bias[0] + s_cross;
        out[row] = 1.0f / (1.0f + expf(-y));
    }
}

extern "C" void kernel_launch(void* const* d_in, const int* in_sizes, int n_in,
                              void* d_out, int out_size, void* d_ws, size_t ws_size,
                              hipStream_t stream) {
    const float* x     = (const float*)d_in[0];  // (4096, 4096)
    const float* cross = (const float*)d_in[1];  // (4096, 1, 64)
    const float* w     = (const float*)d_in[2];  // (1, 4096)
    const float* b     = (const float*)d_in[3];  // (1,)
    float* out = (float*)d_out;                  // (4096, 1)
    float* ws  = (float*)d_ws;

    // ws is re-poisoned to 0xAA before every timed launch: zero what we use.
    hipMemsetAsync(ws, 0, 65 * sizeof(float), stream);

    cross_reduce_kernel<<<64, 256, 0, stream>>>(cross, ws);
    gemv_sigmoid_kernel<<<BATCH, 256, 0, stream>>>(x, w, b, ws, out);
}